// Round 1
// baseline (85.169 us; speedup 1.0000x reference)
//
#include <hip/hip_runtime.h>
#include <math.h>

#define NPTS   8192
#define BATCH  4
#define QPB    1024   // query points per block
#define RCHUNK 1024   // reference points per chunk (staged in LDS)
#define NQT    (NPTS / QPB)     // 8
#define NRC    (NPTS / RCHUNK)  // 8

// Pass 1: for each (dir, batch, query-tile, ref-chunk) block, compute partial
// nearest-neighbor squared distances and atomicMin them into mins[dir][b][q].
__global__ __launch_bounds__(256) void chamfer_min_kernel(
    const float* __restrict__ tpl, const float* __restrict__ src,
    unsigned int* __restrict__ mins)
{
    __shared__ float4 pts[RCHUNK];

    int bid = blockIdx.x;
    int rc  = bid & (NRC - 1);   bid >>= 3;
    int qt  = bid & (NQT - 1);   bid >>= 3;
    int b   = bid & (BATCH - 1); bid >>= 2;
    int dir = bid;               // 0: template->source, 1: source->template

    const float* qbase = (dir ? src : tpl) + (size_t)b * NPTS * 3;
    const float* rbase = (dir ? tpl : src) + (size_t)b * NPTS * 3;

    int t = threadIdx.x;

    // Stage ref chunk into LDS as float4 (xyz + pad) for single ds_read_b128.
    // Thread t loads 12 consecutive floats = points 4t..4t+3 (coalesced).
    const float4* r4 = (const float4*)(rbase + (size_t)rc * RCHUNK * 3);
    float4 A = r4[t * 3 + 0];
    float4 Bv = r4[t * 3 + 1];
    float4 C = r4[t * 3 + 2];
    pts[t * 4 + 0] = make_float4(A.x,  A.y,  A.z,  0.f);
    pts[t * 4 + 1] = make_float4(A.w,  Bv.x, Bv.y, 0.f);
    pts[t * 4 + 2] = make_float4(Bv.z, Bv.w, C.x,  0.f);
    pts[t * 4 + 3] = make_float4(C.y,  C.z,  C.w,  0.f);

    // 4 query points per thread (stride 256 within the 1024-query tile).
    float qx[4], qy[4], qz[4], md[4];
    int q0 = qt * QPB + t;
#pragma unroll
    for (int j = 0; j < 4; ++j) {
        int q = q0 + j * 256;
        qx[j] = qbase[q * 3 + 0];
        qy[j] = qbase[q * 3 + 1];
        qz[j] = qbase[q * 3 + 2];
        md[j] = 3.0e38f;
    }
    __syncthreads();

    // Inner loop: broadcast LDS read (all lanes same address -> no conflicts),
    // 28 VALU ops per ds_read_b128.
#pragma unroll 4
    for (int p = 0; p < RCHUNK; ++p) {
        float4 s = pts[p];
#pragma unroll
        for (int j = 0; j < 4; ++j) {
            float dx = qx[j] - s.x;
            float dy = qy[j] - s.y;
            float dz = qz[j] - s.z;
            float d2 = fmaf(dx, dx, fmaf(dy, dy, dz * dz));
            md[j] = fminf(md[j], d2);
        }
    }

    // d2 >= 0 always, so uint bit pattern is order-preserving.
    unsigned int* m = mins + ((size_t)dir * BATCH + b) * NPTS;
#pragma unroll
    for (int j = 0; j < 4; ++j) {
        atomicMin(&m[q0 + j * 256], __float_as_uint(md[j]));
    }
}

// Pass 2: sqrt + partial sums per block (deterministic fixed slots).
__global__ __launch_bounds__(256) void chamfer_reduce_kernel(
    const unsigned int* __restrict__ mins, float* __restrict__ partials)
{
    int t = threadIdx.x;
    int base = (blockIdx.x * 256 + t) * 4;
    float s0 = 0.f, s1 = 0.f;
#pragma unroll
    for (int k = 0; k < 4; ++k) {
        int i = base + k;
        float v = sqrtf(__uint_as_float(mins[i]));
        if (i < BATCH * NPTS) s0 += v; else s1 += v;
    }
    // wave-64 tree reduce
    for (int off = 32; off > 0; off >>= 1) {
        s0 += __shfl_down(s0, off);
        s1 += __shfl_down(s1, off);
    }
    __shared__ float ws0[4], ws1[4];
    int wave = t >> 6;
    if ((t & 63) == 0) { ws0[wave] = s0; ws1[wave] = s1; }
    __syncthreads();
    if (t == 0) {
        partials[blockIdx.x * 2 + 0] = ws0[0] + ws0[1] + ws0[2] + ws0[3];
        partials[blockIdx.x * 2 + 1] = ws1[0] + ws1[1] + ws1[2] + ws1[3];
    }
}

// Pass 3: deterministic final combine.
__global__ void chamfer_final_kernel(const float* __restrict__ partials,
                                     float* __restrict__ out)
{
    if (threadIdx.x == 0) {
        float s0 = 0.f, s1 = 0.f;
        for (int i = 0; i < 64; ++i) {
            s0 += partials[i * 2 + 0];
            s1 += partials[i * 2 + 1];
        }
        // c01 = s0 / (B*N), c10 = s1 / (B*M); out = 0.5*(c01 + c10)
        out[0] = 0.5f * (s0 + s1) / (float)(BATCH * NPTS);
    }
}

extern "C" void kernel_launch(void* const* d_in, const int* in_sizes, int n_in,
                              void* d_out, int out_size, void* d_ws, size_t ws_size,
                              hipStream_t stream) {
    const float* tpl = (const float*)d_in[0];  // [B, N, 3] fp32
    const float* src = (const float*)d_in[1];  // [B, M, 3] fp32

    unsigned int* mins = (unsigned int*)d_ws;                    // 2*B*NPTS uints
    float* partials = (float*)((char*)d_ws +
                               (size_t)2 * BATCH * NPTS * sizeof(unsigned int));  // 128 floats

    // Init mins to 0x7f7f7f7f (~3.39e38 as float) — larger than any d2.
    hipMemsetAsync(d_ws, 0x7f, (size_t)2 * BATCH * NPTS * sizeof(unsigned int), stream);

    chamfer_min_kernel<<<2 * BATCH * NQT * NRC, 256, 0, stream>>>(tpl, src, mins);
    chamfer_reduce_kernel<<<(2 * BATCH * NPTS) / (256 * 4), 256, 0, stream>>>(mins, partials);
    chamfer_final_kernel<<<1, 64, 0, stream>>>(partials, (float*)d_out);
}

// Round 2
// 60.705 us; speedup vs baseline: 1.4030x; 1.4030x over previous
//
#include <hip/hip_runtime.h>
#include <math.h>

#define NPTS  8192
#define BATCH 4

typedef __bf16 bf16x8 __attribute__((ext_vector_type(8)));
typedef float  f32x16 __attribute__((ext_vector_type(16)));

union U16B { bf16x8 v; uint4 u; };

// Monotone float->uint key: preserves ordering for ALL floats (incl. tiny
// negatives from bf16-split cancellation), so atomicMin on keys == fmin.
__device__ __forceinline__ unsigned enc_key(float f) {
    unsigned b = __float_as_uint(f);
    return (b & 0x80000000u) ? ~b : (b | 0x80000000u);
}
__device__ __forceinline__ float dec_key(unsigned k) {
    unsigned b = (k & 0x80000000u) ? (k ^ 0x80000000u) : ~k;
    return __uint_as_float(b);
}

// Grid: 512 blocks = b(4) x ng4(16) x mg(8); 256 threads = 4 waves.
// Wave covers 4 n-tiles (128 template rows); block covers 32 m-tiles
// (1024 source cols, shared by all 4 waves via LDS-staged g-vectors).
// One mfma_f32_32x32x16_bf16 per (n-tile, m-tile) produces the 32x32 d2
// block directly via the K=16 limb/norm packing.
__global__ __launch_bounds__(256) void chamfer_mfma_kernel(
    const float* __restrict__ tpl, const float* __restrict__ src,
    unsigned* __restrict__ minsT, unsigned* __restrict__ minsS)
{
    __shared__ uint4 gvec[1024 * 3];   // 48 KB: 2x16B g-vec per point, 48B stride (bank spread)
    __shared__ unsigned sminL[1024];   // 4 KB: per-block source-side min keys

    const int bid  = blockIdx.x;
    const int mg   = bid & 7;
    const int ng4  = (bid >> 3) & 15;
    const int b    = bid >> 7;
    const int t    = threadIdx.x;
    const int lane = t & 63;
    const int wave = t >> 6;
    const int khalf = lane >> 5;   // which K-half (k 0-7 or 8-15) this lane supplies
    const int lr   = lane & 31;    // row (A) / col (B) within 32-tile

    const float* tb = tpl + (size_t)b * NPTS * 3;
    const float* sb = src + (size_t)b * NPTS * 3;

#pragma unroll
    for (int i = 0; i < 4; ++i) sminL[t * 4 + i] = 0xFFFFFFFFu;

    // ---- stage source g-vectors: point j -> K=16 bf16 slots (B operand) ----
    // slots: [ -2xh, -2xl, -2xh, -2xl | -2yh, -2yl, -2yh, -2yl ]  (khalf 0)
    //        [ -2zh, -2zl, -2zh, -2zl |   1,    1,  nsh,  nsl  ]  (khalf 1)
    {
        const float4* s4 = (const float4*)(sb + (size_t)mg * 1024 * 3);
        float4 p0 = s4[t * 3 + 0], p1 = s4[t * 3 + 1], p2 = s4[t * 3 + 2];
        float xs[4] = {p0.x, p0.w, p1.z, p2.y};
        float ys[4] = {p0.y, p1.x, p1.w, p2.z};
        float zs[4] = {p0.z, p1.y, p2.x, p2.w};
#pragma unroll
        for (int j = 0; j < 4; ++j) {
            float x = xs[j], y = ys[j], z = zs[j];
            float ns = x * x + y * y + z * z;
            __bf16 xh = (__bf16)x, yh = (__bf16)y, zh = (__bf16)z;
            float xl = x - (float)xh, yl = y - (float)yh, zl = z - (float)zh;
            __bf16 nsh = (__bf16)ns; float nsl = ns - (float)nsh;
            __bf16 xh2 = (__bf16)(-2.0f * (float)xh), xl2 = (__bf16)(-2.0f * xl);
            __bf16 yh2 = (__bf16)(-2.0f * (float)yh), yl2 = (__bf16)(-2.0f * yl);
            __bf16 zh2 = (__bf16)(-2.0f * (float)zh), zl2 = (__bf16)(-2.0f * zl);
            U16B g0, g1;
            g0.v[0] = xh2; g0.v[1] = xl2; g0.v[2] = xh2; g0.v[3] = xl2;
            g0.v[4] = yh2; g0.v[5] = yl2; g0.v[6] = yh2; g0.v[7] = yl2;
            g1.v[0] = zh2; g1.v[1] = zl2; g1.v[2] = zh2; g1.v[3] = zl2;
            g1.v[4] = (__bf16)1.0f; g1.v[5] = (__bf16)1.0f;
            g1.v[6] = nsh; g1.v[7] = (__bf16)nsl;
            int p = t * 4 + j;
            gvec[p * 3 + 0] = g0.u;
            gvec[p * 3 + 1] = g1.u;
        }
    }

    // ---- build A fragments (template side, f-vectors) ----
    // slots: [ xh, xh, xl, xl | yh, yh, yl, yl ]            (khalf 0)
    //        [ zh, zh, zl, zl | nqh, nql, 1, 1 ]            (khalf 1)
    bf16x8 afrag[4];
    const int ntbase = (ng4 * 4 + wave) * 4;
#pragma unroll
    for (int nt = 0; nt < 4; ++nt) {
        int row = (ntbase + nt) * 32 + lr;
        float x = tb[row * 3 + 0], y = tb[row * 3 + 1], z = tb[row * 3 + 2];
        float nq = x * x + y * y + z * z;
        __bf16 xh = (__bf16)x, yh = (__bf16)y, zh = (__bf16)z;
        float xl = x - (float)xh, yl = y - (float)yh, zl = z - (float)zh;
        __bf16 nqh = (__bf16)nq; float nql = nq - (float)nqh;
        bf16x8 f0, f1;
        f0[0] = xh; f0[1] = xh; f0[2] = (__bf16)xl; f0[3] = (__bf16)xl;
        f0[4] = yh; f0[5] = yh; f0[6] = (__bf16)yl; f0[7] = (__bf16)yl;
        f1[0] = zh; f1[1] = zh; f1[2] = (__bf16)zl; f1[3] = (__bf16)zl;
        f1[4] = nqh; f1[5] = (__bf16)nql; f1[6] = (__bf16)1.0f; f1[7] = (__bf16)1.0f;
        afrag[nt] = khalf ? f1 : f0;
    }

    __syncthreads();

    // ---- main loop over the block's 32 m-tiles ----
    float tmin[4][16];
#pragma unroll
    for (int nt = 0; nt < 4; ++nt)
#pragma unroll
        for (int r = 0; r < 16; ++r) tmin[nt][r] = 3.0e38f;

    f32x16 czero;
#pragma unroll
    for (int r = 0; r < 16; ++r) czero[r] = 0.0f;

    U16B bc, bn;
    bc.u = gvec[lr * 3 + khalf];
    for (int mt = 0; mt < 32; ++mt) {
        int nmt = (mt < 31) ? (mt + 1) : 31;
        bn.u = gvec[(nmt * 32 + lr) * 3 + khalf];   // prefetch next B frag
        float sloc = 3.0e38f;
#pragma unroll
        for (int nt = 0; nt < 4; ++nt) {
            f32x16 c = __builtin_amdgcn_mfma_f32_32x32x16_bf16(afrag[nt], bc.v, czero, 0, 0, 0);
            // template-side: per-(row,col-residue) running min, reduced at end
#pragma unroll
            for (int r = 0; r < 16; ++r) tmin[nt][r] = fminf(tmin[nt][r], c[r]);
            // source-side: in-lane tree min over this lane's 16 rows
            float t8[8];
#pragma unroll
            for (int r = 0; r < 8; ++r) t8[r] = fminf(c[r], c[r + 8]);
#pragma unroll
            for (int r = 0; r < 4; ++r) t8[r] = fminf(t8[r], t8[r + 4]);
            t8[0] = fminf(t8[0], t8[2]);
            t8[1] = fminf(t8[1], t8[3]);
            sloc = fminf(sloc, fminf(t8[0], t8[1]));
        }
        // combine the two row-halves (lane <-> lane+32), flush to LDS
        sloc = fminf(sloc, __shfl_xor(sloc, 32));
        if (lane < 32) atomicMin(&sminL[mt * 32 + lr], enc_key(sloc));
        bc = bn;
    }

    // ---- template-side epilogue: butterfly over col-residues 0..31 ----
#pragma unroll
    for (int nt = 0; nt < 4; ++nt)
#pragma unroll
        for (int r = 0; r < 16; ++r) {
            float v = tmin[nt][r];
            v = fminf(v, __shfl_xor(v, 1));
            v = fminf(v, __shfl_xor(v, 2));
            v = fminf(v, __shfl_xor(v, 4));
            v = fminf(v, __shfl_xor(v, 8));
            v = fminf(v, __shfl_xor(v, 16));
            tmin[nt][r] = v;
        }
    if (lr == 0) {   // lanes 0 and 32: one atomic per template row
        unsigned* mT = minsT + (size_t)b * NPTS;
#pragma unroll
        for (int nt = 0; nt < 4; ++nt)
#pragma unroll
            for (int r = 0; r < 16; ++r) {
                int row = (ntbase + nt) * 32 + (r & 3) + 8 * (r >> 2) + 4 * khalf;
                atomicMin(&mT[row], enc_key(tmin[nt][r]));
            }
    }

    __syncthreads();

    // ---- source-side flush: block-combined LDS mins -> global ----
    unsigned* mS = minsS + (size_t)b * NPTS + (size_t)mg * 1024;
#pragma unroll
    for (int i = 0; i < 4; ++i) {
        int idx = t * 4 + i;
        atomicMin(&mS[idx], sminL[idx]);
    }
}

// Pass 2: decode keys, clamp, sqrt, deterministic per-block partial sums.
__global__ __launch_bounds__(256) void chamfer_reduce_kernel(
    const unsigned* __restrict__ mins, float* __restrict__ partials)
{
    int t = threadIdx.x;
    int base = (blockIdx.x * 256 + t) * 4;
    float s0 = 0.f, s1 = 0.f;
#pragma unroll
    for (int k = 0; k < 4; ++k) {
        int i = base + k;
        float v = sqrtf(fmaxf(dec_key(mins[i]), 0.0f));
        if (i < BATCH * NPTS) s0 += v; else s1 += v;
    }
    for (int off = 32; off > 0; off >>= 1) {
        s0 += __shfl_down(s0, off);
        s1 += __shfl_down(s1, off);
    }
    __shared__ float ws0[4], ws1[4];
    int wave = t >> 6;
    if ((t & 63) == 0) { ws0[wave] = s0; ws1[wave] = s1; }
    __syncthreads();
    if (t == 0) {
        partials[blockIdx.x * 2 + 0] = ws0[0] + ws0[1] + ws0[2] + ws0[3];
        partials[blockIdx.x * 2 + 1] = ws1[0] + ws1[1] + ws1[2] + ws1[3];
    }
}

// Pass 3: deterministic final combine.
__global__ void chamfer_final_kernel(const float* __restrict__ partials,
                                     float* __restrict__ out)
{
    if (threadIdx.x == 0) {
        float s0 = 0.f, s1 = 0.f;
        for (int i = 0; i < 64; ++i) {
            s0 += partials[i * 2 + 0];
            s1 += partials[i * 2 + 1];
        }
        out[0] = 0.5f * (s0 + s1) / (float)(BATCH * NPTS);
    }
}

extern "C" void kernel_launch(void* const* d_in, const int* in_sizes, int n_in,
                              void* d_out, int out_size, void* d_ws, size_t ws_size,
                              hipStream_t stream) {
    const float* tpl = (const float*)d_in[0];  // [B, N, 3] fp32
    const float* src = (const float*)d_in[1];  // [B, M, 3] fp32

    unsigned* mins = (unsigned*)d_ws;                         // [2][B][8192] keys
    float* partials = (float*)((char*)d_ws + (size_t)2 * BATCH * NPTS * sizeof(unsigned));

    hipMemsetAsync(mins, 0xFF, (size_t)2 * BATCH * NPTS * sizeof(unsigned), stream);

    chamfer_mfma_kernel<<<512, 256, 0, stream>>>(tpl, src, mins, mins + BATCH * NPTS);
    chamfer_reduce_kernel<<<(2 * BATCH * NPTS) / (256 * 4), 256, 0, stream>>>(mins, partials);
    chamfer_final_kernel<<<1, 64, 0, stream>>>(partials, (float*)d_out);
}